// Round 3
// baseline (1537.855 us; speedup 1.0000x reference)
//
#include <hip/hip_runtime.h>
#include <stdint.h>

typedef __bf16 bf16_t;
typedef __bf16 bf16x8 __attribute__((ext_vector_type(8)));
typedef __bf16 bf16x4 __attribute__((ext_vector_type(4)));
typedef float  f32x4  __attribute__((ext_vector_type(4)));

#define MFMA16(a, b, c) __builtin_amdgcn_mfma_f32_16x16x32_bf16((a), (b), (c), 0, 0, 0)

// ---------------------------------------------------------------------------
// RMSNorm (fp32 in -> bf16 out): one block per token row (H=2048), 256 thr x 8
// ---------------------------------------------------------------------------
__global__ __launch_bounds__(256)
void rmsnorm_f32(const float* __restrict__ X, const float* __restrict__ Wt,
                 bf16_t* __restrict__ Y)
{
    __shared__ float red[4];
    const int tid = threadIdx.x;
    const size_t row = blockIdx.x;
    const float* x = X + row * 2048;

    f32x4 x0 = *(const f32x4*)(x + tid * 8);
    f32x4 x1 = *(const f32x4*)(x + tid * 8 + 4);
    float ss = 0.f;
#pragma unroll
    for (int e = 0; e < 4; ++e) ss += x0[e] * x0[e] + x1[e] * x1[e];
#pragma unroll
    for (int off = 32; off; off >>= 1) ss += __shfl_xor(ss, off, 64);
    if ((tid & 63) == 0) red[tid >> 6] = ss;
    __syncthreads();
    float tot = red[0] + red[1] + red[2] + red[3];
    float scale = rsqrtf(tot * (1.f / 2048.f) + 1e-6f);

    f32x4 w0 = *(const f32x4*)(Wt + tid * 8);
    f32x4 w1 = *(const f32x4*)(Wt + tid * 8 + 4);
    bf16x8 yv;
#pragma unroll
    for (int e = 0; e < 4; ++e) {
        yv[e]     = (bf16_t)(x0[e] * scale * w0[e]);
        yv[e + 4] = (bf16_t)(x1[e] * scale * w1[e]);
    }
    *(bf16x8*)(Y + row * 2048 + tid * 8) = yv;
}

// ---------------------------------------------------------------------------
// RMSNorm (bf16 in -> bf16 out), fp32 gamma
// ---------------------------------------------------------------------------
__global__ __launch_bounds__(256)
void rmsnorm_bf16(const bf16_t* __restrict__ X, const float* __restrict__ Wt,
                  bf16_t* __restrict__ Y)
{
    __shared__ float red[4];
    const int tid = threadIdx.x;
    const size_t row = blockIdx.x;

    bf16x8 xv = *(const bf16x8*)(X + row * 2048 + tid * 8);
    float xf[8];
    float ss = 0.f;
#pragma unroll
    for (int e = 0; e < 8; ++e) { xf[e] = (float)xv[e]; ss += xf[e] * xf[e]; }
#pragma unroll
    for (int off = 32; off; off >>= 1) ss += __shfl_xor(ss, off, 64);
    if ((tid & 63) == 0) red[tid >> 6] = ss;
    __syncthreads();
    float tot = red[0] + red[1] + red[2] + red[3];
    float scale = rsqrtf(tot * (1.f / 2048.f) + 1e-6f);

    f32x4 w0 = *(const f32x4*)(Wt + tid * 8);
    f32x4 w1 = *(const f32x4*)(Wt + tid * 8 + 4);
    bf16x8 yv;
#pragma unroll
    for (int e = 0; e < 4; ++e) {
        yv[e]     = (bf16_t)(xf[e] * scale * w0[e]);
        yv[e + 4] = (bf16_t)(xf[e + 4] * scale * w1[e]);
    }
    *(bf16x8*)(Y + row * 2048 + tid * 8) = yv;
}

// ---------------------------------------------------------------------------
// GEMM: acc = A[M,K](bf16) @ W[N,K](fp32)^T, bf16 MFMA, fp32 acc.
// mode 0: Cb = acc | mode 1: Cb = acc + Rf(fp32) | mode 2: Cf = acc + Rb(bf16)
// 128x128 tile, BK=64, 256 thr = 4 waves; W converted fp32->bf16 in staging.
// ---------------------------------------------------------------------------
__global__ __launch_bounds__(256, 2)
void gemm_bt(const bf16_t* __restrict__ A, const float* __restrict__ W,
             const float* __restrict__ Rf, const bf16_t* __restrict__ Rb,
             bf16_t* __restrict__ Cb, float* __restrict__ Cf,
             int M, int N, int K, int mode)
{
    __shared__ bf16_t As[128 * 64];
    __shared__ bf16_t Ws[128 * 64];

    const int tid  = threadIdx.x;
    const int lane = tid & 63, wave = tid >> 6;
    const int quad = lane >> 4, l16 = lane & 15;
    const int m0 = blockIdx.y * 128, n0 = blockIdx.x * 128;
    const int wm = (wave >> 1) * 64, wn = (wave & 1) * 64;

    f32x4 acc[4][4] = {};

    for (int k0 = 0; k0 < K; k0 += 64) {
        bf16x8 ra[4];
        bf16x4 rw[8];
#pragma unroll
        for (int i = 0; i < 4; ++i) {
            int u = i * 256 + tid;          // 16B unit in [0,1024)
            int r = u >> 3, c = (u & 7) << 3;
            ra[i] = *(const bf16x8*)(A + (size_t)(m0 + r) * K + k0 + c);
        }
#pragma unroll
        for (int i = 0; i < 8; ++i) {
            int u = i * 256 + tid;          // float4 unit in [0,2048)
            int r = u >> 4, c = (u & 15) << 2;
            f32x4 w4 = *(const f32x4*)(W + (size_t)(n0 + r) * K + k0 + c);
#pragma unroll
            for (int e = 0; e < 4; ++e) rw[i][e] = (bf16_t)w4[e];
        }
        __syncthreads();                     // prior compute done before overwrite
#pragma unroll
        for (int i = 0; i < 4; ++i)
            *(bf16x8*)(As + (i * 256 + tid) * 8) = ra[i];
#pragma unroll
        for (int i = 0; i < 8; ++i)
            *(bf16x4*)(Ws + (i * 256 + tid) * 4) = rw[i];
        __syncthreads();

#pragma unroll
        for (int ks = 0; ks < 64; ks += 32) {
            bf16x8 af[4], bfr[4];
#pragma unroll
            for (int i = 0; i < 4; ++i)
                af[i] = *(const bf16x8*)(As + (wm + i * 16 + l16) * 64 + ks + quad * 8);
#pragma unroll
            for (int j = 0; j < 4; ++j)
                bfr[j] = *(const bf16x8*)(Ws + (wn + j * 16 + l16) * 64 + ks + quad * 8);
#pragma unroll
            for (int i = 0; i < 4; ++i)
#pragma unroll
                for (int j = 0; j < 4; ++j)
                    acc[i][j] = MFMA16(af[i], bfr[j], acc[i][j]);
        }
    }

    // epilogue: C/D layout row = quad*4+reg, col = lane&15
#pragma unroll
    for (int i = 0; i < 4; ++i)
#pragma unroll
        for (int j = 0; j < 4; ++j)
#pragma unroll
            for (int r = 0; r < 4; ++r) {
                size_t row = (size_t)(m0 + wm + i * 16 + quad * 4 + r);
                size_t col = (size_t)(n0 + wn + j * 16 + l16);
                float v = acc[i][j][r];
                if (mode == 1) v += Rf[row * (size_t)N + col];
                if (mode == 2)
                    Cf[row * (size_t)N + col] = v + (float)Rb[row * (size_t)N + col];
                else
                    Cb[row * (size_t)N + col] = (bf16_t)v;
            }
}

// ---------------------------------------------------------------------------
// Fused gate+up GEMM + SwiGLU: C = silu(A@G^T) * (A@U^T), G/U fp32 weights.
// ---------------------------------------------------------------------------
__global__ __launch_bounds__(256, 2)
void gemm_gateup(const bf16_t* __restrict__ A, const float* __restrict__ G,
                 const float* __restrict__ U, bf16_t* __restrict__ C,
                 int M, int N, int K)
{
    __shared__ bf16_t As[128 * 64];
    __shared__ bf16_t Gs[128 * 64];
    __shared__ bf16_t Us[128 * 64];

    const int tid  = threadIdx.x;
    const int lane = tid & 63, wave = tid >> 6;
    const int quad = lane >> 4, l16 = lane & 15;
    const int m0 = blockIdx.y * 128, n0 = blockIdx.x * 128;
    const int wm = (wave >> 1) * 64, wn = (wave & 1) * 64;

    f32x4 accg[4][4] = {};
    f32x4 accu[4][4] = {};

    for (int k0 = 0; k0 < K; k0 += 64) {
        bf16x8 ra[4];
        bf16x4 rg[8], ru[8];
#pragma unroll
        for (int i = 0; i < 4; ++i) {
            int u = i * 256 + tid;
            int r = u >> 3, c = (u & 7) << 3;
            ra[i] = *(const bf16x8*)(A + (size_t)(m0 + r) * K + k0 + c);
        }
#pragma unroll
        for (int i = 0; i < 8; ++i) {
            int u = i * 256 + tid;
            int r = u >> 4, c = (u & 15) << 2;
            f32x4 g4 = *(const f32x4*)(G + (size_t)(n0 + r) * K + k0 + c);
            f32x4 u4 = *(const f32x4*)(U + (size_t)(n0 + r) * K + k0 + c);
#pragma unroll
            for (int e = 0; e < 4; ++e) { rg[i][e] = (bf16_t)g4[e]; ru[i][e] = (bf16_t)u4[e]; }
        }
        __syncthreads();
#pragma unroll
        for (int i = 0; i < 4; ++i)
            *(bf16x8*)(As + (i * 256 + tid) * 8) = ra[i];
#pragma unroll
        for (int i = 0; i < 8; ++i) {
            *(bf16x4*)(Gs + (i * 256 + tid) * 4) = rg[i];
            *(bf16x4*)(Us + (i * 256 + tid) * 4) = ru[i];
        }
        __syncthreads();

#pragma unroll
        for (int ks = 0; ks < 64; ks += 32) {
            bf16x8 af[4], bg[4], bu[4];
#pragma unroll
            for (int i = 0; i < 4; ++i)
                af[i] = *(const bf16x8*)(As + (wm + i * 16 + l16) * 64 + ks + quad * 8);
#pragma unroll
            for (int j = 0; j < 4; ++j) {
                bg[j] = *(const bf16x8*)(Gs + (wn + j * 16 + l16) * 64 + ks + quad * 8);
                bu[j] = *(const bf16x8*)(Us + (wn + j * 16 + l16) * 64 + ks + quad * 8);
            }
#pragma unroll
            for (int i = 0; i < 4; ++i)
#pragma unroll
                for (int j = 0; j < 4; ++j) {
                    accg[i][j] = MFMA16(af[i], bg[j], accg[i][j]);
                    accu[i][j] = MFMA16(af[i], bu[j], accu[i][j]);
                }
        }
    }

#pragma unroll
    for (int i = 0; i < 4; ++i)
#pragma unroll
        for (int j = 0; j < 4; ++j)
#pragma unroll
            for (int r = 0; r < 4; ++r) {
                size_t row = (size_t)(m0 + wm + i * 16 + quad * 4 + r);
                size_t col = (size_t)(n0 + wn + j * 16 + l16);
                float g = accg[i][j][r];
                float u = accu[i][j][r];
                float sig = 1.f / (1.f + __expf(fminf(-g, 80.f)));   // NaN-free silu
                C[row * (size_t)N + col] = (bf16_t)(g * sig * u);
            }
}

// ---------------------------------------------------------------------------
// Flash attention fwd, causal, GQA (kv head = h>>1). bf16 MFMA, fp32 softmax.
// ---------------------------------------------------------------------------
__global__ __launch_bounds__(256, 2)
void attn_fwd(const bf16_t* __restrict__ Q, const bf16_t* __restrict__ Kg,
              const bf16_t* __restrict__ Vg, bf16_t* __restrict__ O)
{
    __shared__ bf16_t Ks[64 * 128];
    __shared__ bf16_t Vt[128 * 64];
    __shared__ bf16_t Pl[4][16 * 64];

    const int tid  = threadIdx.x;
    const int lane = tid & 63, wave = tid >> 6;
    const int quad = lane >> 4, l16 = lane & 15;
    const int bh = blockIdx.y, b = bh >> 4, h = bh & 15;
    const int q0 = blockIdx.x * 64;

    const bf16_t* Qh = Q  + (size_t)b * 2048 * 2048 + (size_t)h * 128;
    const bf16_t* Kh = Kg + (size_t)b * 2048 * 1024 + (size_t)(h >> 1) * 128;
    const bf16_t* Vh = Vg + (size_t)b * 2048 * 1024 + (size_t)(h >> 1) * 128;

    bf16x8 aq[4];
#pragma unroll
    for (int ks = 0; ks < 4; ++ks)
        aq[ks] = *(const bf16x8*)(Qh + (size_t)(q0 + wave * 16 + l16) * 2048 + ks * 32 + quad * 8);

    float m_r[4] = { -30000.f, -30000.f, -30000.f, -30000.f };
    float l_r[4] = { 0.f, 0.f, 0.f, 0.f };
    f32x4 acc_o[8] = {};

    const float scale = 0.08838834764831845f;   // 1/sqrt(128)
    const int ntiles = blockIdx.x + 1;          // causal: kv tiles 0..qtile

    for (int t = 0; t < ntiles; ++t) {
        const int kv0 = t * 64;
        __syncthreads();
#pragma unroll
        for (int i = 0; i < 4; ++i) {
            int u = i * 256 + tid;               // 16B unit in [0,1024)
            int rk = u >> 4, c = (u & 15) << 3;
            bf16x8 kv8 = *(const bf16x8*)(Kh + (size_t)(kv0 + rk) * 1024 + c);
            *(bf16x8*)(Ks + u * 8) = kv8;
            bf16x8 vv = *(const bf16x8*)(Vh + (size_t)(kv0 + rk) * 1024 + c);
#pragma unroll
            for (int e = 0; e < 8; ++e) Vt[(c + e) * 64 + rk] = vv[e];
        }
        __syncthreads();

        f32x4 accs[4] = {};
#pragma unroll
        for (int ks = 0; ks < 4; ++ks)
#pragma unroll
            for (int j = 0; j < 4; ++j) {
                bf16x8 bk = *(const bf16x8*)(Ks + (j * 16 + l16) * 128 + ks * 32 + quad * 8);
                accs[j] = MFMA16(aq[ks], bk, accs[j]);
            }

#pragma unroll
        for (int r = 0; r < 4; ++r) {
            const int qrow = q0 + wave * 16 + quad * 4 + r;
            float s[4];
            float mx = -30000.f;
#pragma unroll
            for (int j = 0; j < 4; ++j) {
                s[j] = accs[j][r] * scale;
                if (kv0 + j * 16 + l16 > qrow) s[j] = -30000.f;   // causal mask
                mx = fmaxf(mx, s[j]);
            }
            mx = fmaxf(mx, __shfl_xor(mx, 1, 64));
            mx = fmaxf(mx, __shfl_xor(mx, 2, 64));
            mx = fmaxf(mx, __shfl_xor(mx, 4, 64));
            mx = fmaxf(mx, __shfl_xor(mx, 8, 64));
            float mnew  = fmaxf(m_r[r], mx);
            float alpha = __expf(fmaxf(m_r[r] - mnew, -80.f));
            float rs = 0.f;
#pragma unroll
            for (int j = 0; j < 4; ++j) {
                float p = __expf(fmaxf(s[j] - mnew, -80.f));
                rs += p;
                Pl[wave][(quad * 4 + r) * 64 + j * 16 + l16] = (bf16_t)p;
            }
            rs += __shfl_xor(rs, 1, 64);
            rs += __shfl_xor(rs, 2, 64);
            rs += __shfl_xor(rs, 4, 64);
            rs += __shfl_xor(rs, 8, 64);
            l_r[r] = l_r[r] * alpha + rs;
            m_r[r] = mnew;
#pragma unroll
            for (int nt = 0; nt < 8; ++nt) acc_o[nt][r] *= alpha;
        }

        __syncthreads();   // P writes visible before PV reads

#pragma unroll
        for (int ks2 = 0; ks2 < 2; ++ks2) {
            bf16x8 ap = *(const bf16x8*)(&Pl[wave][l16 * 64 + ks2 * 32 + quad * 8]);
#pragma unroll
            for (int nt = 0; nt < 8; ++nt) {
                bf16x8 bv = *(const bf16x8*)(Vt + (nt * 16 + l16) * 64 + ks2 * 32 + quad * 8);
                acc_o[nt] = MFMA16(ap, bv, acc_o[nt]);
            }
        }
    }

#pragma unroll
    for (int r = 0; r < 4; ++r) {
        float inv = 1.f / fmaxf(l_r[r], 1e-30f);
        size_t orow = (size_t)b * 2048 + q0 + wave * 16 + quad * 4 + r;
#pragma unroll
        for (int nt = 0; nt < 8; ++nt)
            O[orow * 2048 + h * 128 + nt * 16 + l16] = (bf16_t)(acc_o[nt][r] * inv);
    }
}

// ---------------------------------------------------------------------------
// Launch. All inputs fp32 (reference dtypes); output fp32; bf16 MFMA internal.
// Workspace peak ~39.1M bf16 elements = 78.2 MB.
// ---------------------------------------------------------------------------
extern "C" void kernel_launch(void* const* d_in, const int* in_sizes, int n_in,
                              void* d_out, int out_size, void* d_ws, size_t ws_size,
                              hipStream_t stream)
{
    const float* x   = (const float*)d_in[0];
    // d_in[1] = attention_mask (causal) — applied analytically
    const float* qw  = (const float*)d_in[2];
    const float* kw  = (const float*)d_in[3];
    const float* vw  = (const float*)d_in[4];
    const float* ow  = (const float*)d_in[5];
    const float* gw  = (const float*)d_in[6];
    const float* uw  = (const float*)d_in[7];
    const float* dw  = (const float*)d_in[8];
    const float* ln1 = (const float*)d_in[9];
    const float* ln2 = (const float*)d_in[10];
    float*  out = (float*)d_out;
    bf16_t* ws  = (bf16_t*)d_ws;

    const size_t ME = 1ull << 20;        // 1M elements
    bf16_t* h1 = ws;                     // [0, 8M)   ln1(x), later ln2(h)
    bf16_t* qb = ws + 8  * ME;           // [8,16M)   q, later hb
    bf16_t* kb = ws + 16 * ME;           // [16,20M)  k
    bf16_t* vb = ws + 20 * ME;           // [20,24M)  v
    bf16_t* ab = (bf16_t*)d_out;         // attn out: d_out as bf16 scratch
    bf16_t* hb = ws + 8  * ME;           // [8,16M)   h = x + attn (q dead)
    bf16_t* gb = ws + 16 * ME;           // [16,39.1M) swiglu out (k/v dead)

    dim3 blk(256);
    rmsnorm_f32<<<4096, blk, 0, stream>>>(x, ln1, h1);
    gemm_bt<<<dim3(16, 32), blk, 0, stream>>>(h1, qw, nullptr, nullptr, qb, nullptr, 4096, 2048, 2048, 0);
    gemm_bt<<<dim3( 8, 32), blk, 0, stream>>>(h1, kw, nullptr, nullptr, kb, nullptr, 4096, 1024, 2048, 0);
    gemm_bt<<<dim3( 8, 32), blk, 0, stream>>>(h1, vw, nullptr, nullptr, vb, nullptr, 4096, 1024, 2048, 0);
    attn_fwd<<<dim3(32, 32), blk, 0, stream>>>(qb, kb, vb, ab);
    gemm_bt<<<dim3(16, 32), blk, 0, stream>>>(ab, ow, x, nullptr, hb, nullptr, 4096, 2048, 2048, 1);
    rmsnorm_bf16<<<4096, blk, 0, stream>>>(hb, ln2, h1);
    gemm_gateup<<<dim3(44, 32), blk, 0, stream>>>(h1, gw, uw, gb, 4096, 5632, 2048);
    gemm_bt<<<dim3(16, 32), blk, 0, stream>>>(gb, dw, nullptr, hb, nullptr, out, 4096, 2048, 5632, 2);
}

// Round 4
// 1207.565 us; speedup vs baseline: 1.2735x; 1.2735x over previous
//
#include <hip/hip_runtime.h>
#include <stdint.h>

typedef __bf16 bf16_t;
typedef __bf16 bf16x8 __attribute__((ext_vector_type(8)));
typedef __bf16 bf16x4 __attribute__((ext_vector_type(4)));
typedef float  f32x4  __attribute__((ext_vector_type(4)));

#define MFMA16(a, b, c) __builtin_amdgcn_mfma_f32_16x16x32_bf16((a), (b), (c), 0, 0, 0)

// ---------------------------------------------------------------------------
// RMSNorm (fp32 in -> bf16 out): one block per token row (H=2048), 256 thr x 8
// ---------------------------------------------------------------------------
__global__ __launch_bounds__(256)
void rmsnorm_f32(const float* __restrict__ X, const float* __restrict__ Wt,
                 bf16_t* __restrict__ Y)
{
    __shared__ float red[4];
    const int tid = threadIdx.x;
    const size_t row = blockIdx.x;
    const float* x = X + row * 2048;

    f32x4 x0 = *(const f32x4*)(x + tid * 8);
    f32x4 x1 = *(const f32x4*)(x + tid * 8 + 4);
    float ss = 0.f;
#pragma unroll
    for (int e = 0; e < 4; ++e) ss += x0[e] * x0[e] + x1[e] * x1[e];
#pragma unroll
    for (int off = 32; off; off >>= 1) ss += __shfl_xor(ss, off, 64);
    if ((tid & 63) == 0) red[tid >> 6] = ss;
    __syncthreads();
    float tot = red[0] + red[1] + red[2] + red[3];
    float scale = rsqrtf(tot * (1.f / 2048.f) + 1e-6f);

    f32x4 w0 = *(const f32x4*)(Wt + tid * 8);
    f32x4 w1 = *(const f32x4*)(Wt + tid * 8 + 4);
    bf16x8 yv;
#pragma unroll
    for (int e = 0; e < 4; ++e) {
        yv[e]     = (bf16_t)(x0[e] * scale * w0[e]);
        yv[e + 4] = (bf16_t)(x1[e] * scale * w1[e]);
    }
    *(bf16x8*)(Y + row * 2048 + tid * 8) = yv;
}

// ---------------------------------------------------------------------------
// RMSNorm (bf16 in -> bf16 out), fp32 gamma
// ---------------------------------------------------------------------------
__global__ __launch_bounds__(256)
void rmsnorm_bf16(const bf16_t* __restrict__ X, const float* __restrict__ Wt,
                  bf16_t* __restrict__ Y)
{
    __shared__ float red[4];
    const int tid = threadIdx.x;
    const size_t row = blockIdx.x;

    bf16x8 xv = *(const bf16x8*)(X + row * 2048 + tid * 8);
    float xf[8];
    float ss = 0.f;
#pragma unroll
    for (int e = 0; e < 8; ++e) { xf[e] = (float)xv[e]; ss += xf[e] * xf[e]; }
#pragma unroll
    for (int off = 32; off; off >>= 1) ss += __shfl_xor(ss, off, 64);
    if ((tid & 63) == 0) red[tid >> 6] = ss;
    __syncthreads();
    float tot = red[0] + red[1] + red[2] + red[3];
    float scale = rsqrtf(tot * (1.f / 2048.f) + 1e-6f);

    f32x4 w0 = *(const f32x4*)(Wt + tid * 8);
    f32x4 w1 = *(const f32x4*)(Wt + tid * 8 + 4);
    bf16x8 yv;
#pragma unroll
    for (int e = 0; e < 4; ++e) {
        yv[e]     = (bf16_t)(xf[e] * scale * w0[e]);
        yv[e + 4] = (bf16_t)(xf[e + 4] * scale * w1[e]);
    }
    *(bf16x8*)(Y + row * 2048 + tid * 8) = yv;
}

// ---------------------------------------------------------------------------
// GEMM: acc = A[M,K](bf16) @ W[N,K](fp32)^T, bf16 MFMA, fp32 acc.
// mode 0: Cb = acc | mode 1: Cb = acc + Rf(fp32) | mode 2: Cf = acc + Rb(bf16)
// ---------------------------------------------------------------------------
__global__ __launch_bounds__(256, 2)
void gemm_bt(const bf16_t* __restrict__ A, const float* __restrict__ W,
             const float* __restrict__ Rf, const bf16_t* __restrict__ Rb,
             bf16_t* __restrict__ Cb, float* __restrict__ Cf,
             int M, int N, int K, int mode)
{
    __shared__ bf16_t As[128 * 64];
    __shared__ bf16_t Ws[128 * 64];

    const int tid  = threadIdx.x;
    const int lane = tid & 63, wave = tid >> 6;
    const int quad = lane >> 4, l16 = lane & 15;
    const int m0 = blockIdx.y * 128, n0 = blockIdx.x * 128;
    const int wm = (wave >> 1) * 64, wn = (wave & 1) * 64;

    f32x4 acc[4][4] = {};

    for (int k0 = 0; k0 < K; k0 += 64) {
        bf16x8 ra[4];
        bf16x4 rw[8];
#pragma unroll
        for (int i = 0; i < 4; ++i) {
            int u = i * 256 + tid;          // 16B unit in [0,1024)
            int r = u >> 3, c = (u & 7) << 3;
            ra[i] = *(const bf16x8*)(A + (size_t)(m0 + r) * K + k0 + c);
        }
#pragma unroll
        for (int i = 0; i < 8; ++i) {
            int u = i * 256 + tid;          // float4 unit in [0,2048)
            int r = u >> 4, c = (u & 15) << 2;
            f32x4 w4 = *(const f32x4*)(W + (size_t)(n0 + r) * K + k0 + c);
#pragma unroll
            for (int e = 0; e < 4; ++e) rw[i][e] = (bf16_t)w4[e];
        }
        __syncthreads();                     // prior compute done before overwrite
#pragma unroll
        for (int i = 0; i < 4; ++i)
            *(bf16x8*)(As + (i * 256 + tid) * 8) = ra[i];
#pragma unroll
        for (int i = 0; i < 8; ++i)
            *(bf16x4*)(Ws + (i * 256 + tid) * 4) = rw[i];
        __syncthreads();

#pragma unroll
        for (int ks = 0; ks < 64; ks += 32) {
            bf16x8 af[4], bfr[4];
#pragma unroll
            for (int i = 0; i < 4; ++i)
                af[i] = *(const bf16x8*)(As + (wm + i * 16 + l16) * 64 + ks + quad * 8);
#pragma unroll
            for (int j = 0; j < 4; ++j)
                bfr[j] = *(const bf16x8*)(Ws + (wn + j * 16 + l16) * 64 + ks + quad * 8);
#pragma unroll
            for (int i = 0; i < 4; ++i)
#pragma unroll
                for (int j = 0; j < 4; ++j)
                    acc[i][j] = MFMA16(af[i], bfr[j], acc[i][j]);
        }
    }

    // epilogue: C/D layout row = quad*4+reg, col = lane&15
#pragma unroll
    for (int i = 0; i < 4; ++i)
#pragma unroll
        for (int j = 0; j < 4; ++j)
#pragma unroll
            for (int r = 0; r < 4; ++r) {
                size_t row = (size_t)(m0 + wm + i * 16 + quad * 4 + r);
                size_t col = (size_t)(n0 + wn + j * 16 + l16);
                float v = acc[i][j][r];
                if (mode == 1) v += Rf[row * (size_t)N + col];
                if (mode == 2)
                    Cf[row * (size_t)N + col] = v + (float)Rb[row * (size_t)N + col];
                else
                    Cb[row * (size_t)N + col] = (bf16_t)v;
            }
}

// ---------------------------------------------------------------------------
// Fused gate+up GEMM + SwiGLU: C = silu(A@G^T) * (A@U^T), G/U fp32 weights.
// ---------------------------------------------------------------------------
__global__ __launch_bounds__(256, 2)
void gemm_gateup(const bf16_t* __restrict__ A, const float* __restrict__ G,
                 const float* __restrict__ U, bf16_t* __restrict__ C,
                 int M, int N, int K)
{
    __shared__ bf16_t As[128 * 64];
    __shared__ bf16_t Gs[128 * 64];
    __shared__ bf16_t Us[128 * 64];

    const int tid  = threadIdx.x;
    const int lane = tid & 63, wave = tid >> 6;
    const int quad = lane >> 4, l16 = lane & 15;
    const int m0 = blockIdx.y * 128, n0 = blockIdx.x * 128;
    const int wm = (wave >> 1) * 64, wn = (wave & 1) * 64;

    f32x4 accg[4][4] = {};
    f32x4 accu[4][4] = {};

    for (int k0 = 0; k0 < K; k0 += 64) {
        bf16x8 ra[4];
        bf16x4 rg[8], ru[8];
#pragma unroll
        for (int i = 0; i < 4; ++i) {
            int u = i * 256 + tid;
            int r = u >> 3, c = (u & 7) << 3;
            ra[i] = *(const bf16x8*)(A + (size_t)(m0 + r) * K + k0 + c);
        }
#pragma unroll
        for (int i = 0; i < 8; ++i) {
            int u = i * 256 + tid;
            int r = u >> 4, c = (u & 15) << 2;
            f32x4 g4 = *(const f32x4*)(G + (size_t)(n0 + r) * K + k0 + c);
            f32x4 u4 = *(const f32x4*)(U + (size_t)(n0 + r) * K + k0 + c);
#pragma unroll
            for (int e = 0; e < 4; ++e) { rg[i][e] = (bf16_t)g4[e]; ru[i][e] = (bf16_t)u4[e]; }
        }
        __syncthreads();
#pragma unroll
        for (int i = 0; i < 4; ++i)
            *(bf16x8*)(As + (i * 256 + tid) * 8) = ra[i];
#pragma unroll
        for (int i = 0; i < 8; ++i) {
            *(bf16x4*)(Gs + (i * 256 + tid) * 4) = rg[i];
            *(bf16x4*)(Us + (i * 256 + tid) * 4) = ru[i];
        }
        __syncthreads();

#pragma unroll
        for (int ks = 0; ks < 64; ks += 32) {
            bf16x8 af[4], bg[4], bu[4];
#pragma unroll
            for (int i = 0; i < 4; ++i)
                af[i] = *(const bf16x8*)(As + (wm + i * 16 + l16) * 64 + ks + quad * 8);
#pragma unroll
            for (int j = 0; j < 4; ++j) {
                bg[j] = *(const bf16x8*)(Gs + (wn + j * 16 + l16) * 64 + ks + quad * 8);
                bu[j] = *(const bf16x8*)(Us + (wn + j * 16 + l16) * 64 + ks + quad * 8);
            }
#pragma unroll
            for (int i = 0; i < 4; ++i)
#pragma unroll
                for (int j = 0; j < 4; ++j) {
                    accg[i][j] = MFMA16(af[i], bg[j], accg[i][j]);
                    accu[i][j] = MFMA16(af[i], bu[j], accu[i][j]);
                }
        }
    }

#pragma unroll
    for (int i = 0; i < 4; ++i)
#pragma unroll
        for (int j = 0; j < 4; ++j)
#pragma unroll
            for (int r = 0; r < 4; ++r) {
                size_t row = (size_t)(m0 + wm + i * 16 + quad * 4 + r);
                size_t col = (size_t)(n0 + wn + j * 16 + l16);
                float g = accg[i][j][r];
                float u = accu[i][j][r];
                float sig = 1.f / (1.f + __expf(fminf(-g, 80.f)));   // NaN-free silu
                C[row * (size_t)N + col] = (bf16_t)(g * sig * u);
            }
}

// ---------------------------------------------------------------------------
// Flash attention fwd, causal, GQA (kv head = h>>1). bf16 MFMA, fp32 softmax.
// Round-4 changes:
//  * V staged transposed via direct global scalar loads (64-lane-contiguous d,
//    coalesced 128B) + XOR-swizzled ds_write_b128 (kb ^= d&7): conflict-free.
//  * Pl padded 64->72: write conflicts 4-way -> 2-way (free), reads clean.
//  * Causal load balance: grid.x=16, block runs q-tiles bx and 31-bx
//    (exactly 33 kv-tiles per block).
// ---------------------------------------------------------------------------
__global__ __launch_bounds__(256, 2)
void attn_fwd(const bf16_t* __restrict__ Q, const bf16_t* __restrict__ Kg,
              const bf16_t* __restrict__ Vg, bf16_t* __restrict__ O)
{
    __shared__ bf16_t Ks[64 * 128];
    __shared__ bf16_t Vt[128 * 64];      // Vt[d][k], k-blocks XOR-swizzled by d&7
    __shared__ bf16_t Pl[4][16 * 72];    // padded stride 72

    const int tid  = threadIdx.x;
    const int lane = tid & 63, wave = tid >> 6;
    const int quad = lane >> 4, l16 = lane & 15;
    const int bh = blockIdx.y, b = bh >> 4, h = bh & 15;

    const bf16_t* Qh = Q  + (size_t)b * 2048 * 2048 + (size_t)h * 128;
    const bf16_t* Kh = Kg + (size_t)b * 2048 * 1024 + (size_t)(h >> 1) * 128;
    const bf16_t* Vh = Vg + (size_t)b * 2048 * 1024 + (size_t)(h >> 1) * 128;

    const float scale = 0.08838834764831845f;   // 1/sqrt(128)

#pragma unroll 1
    for (int pass = 0; pass < 2; ++pass) {
        const int qt = pass ? (31 - (int)blockIdx.x) : (int)blockIdx.x;
        const int q0 = qt * 64;

        // this wave's Q fragments (rows q0 + wave*16 + l16, A-layout)
        bf16x8 aq[4];
#pragma unroll
        for (int ks = 0; ks < 4; ++ks)
            aq[ks] = *(const bf16x8*)(Qh + (size_t)(q0 + wave * 16 + l16) * 2048 + ks * 32 + quad * 8);

        float m_r[4] = { -30000.f, -30000.f, -30000.f, -30000.f };
        float l_r[4] = { 0.f, 0.f, 0.f, 0.f };
        f32x4 acc_o[8] = {};

        const int ntiles = qt + 1;               // causal: kv tiles 0..qt

        for (int t = 0; t < ntiles; ++t) {
            const int kv0 = t * 64;
            __syncthreads();                     // prior reads of Ks/Vt done
            // K tile: vectorized, conflict-free
#pragma unroll
            for (int i = 0; i < 4; ++i) {
                int u = i * 256 + tid;           // 16B unit in [0,1024)
                int rk = u >> 4, c = (u & 15) << 3;
                *(bf16x8*)(Ks + u * 8) =
                    *(const bf16x8*)(Kh + (size_t)(kv0 + rk) * 1024 + c);
            }
            // V tile, transposed: lane gathers 8 k-contiguous scalars for one d
            // (64 consecutive d per wave -> 128B coalesced rows, L2-hot), then
            // one swizzled b128 LDS write (conflict-free).
#pragma unroll
            for (int it = 0; it < 4; ++it) {
                int v = it * 256 + tid;
                int d = v & 127, kb = v >> 7;    // kb in [0,8)
                bf16x8 vt8;
#pragma unroll
                for (int j = 0; j < 8; ++j)
                    vt8[j] = Vh[(size_t)(kv0 + kb * 8 + j) * 1024 + d];
                *(bf16x8*)(Vt + d * 64 + ((kb ^ (d & 7)) << 3)) = vt8;
            }
            __syncthreads();

            // S = Q K^T  (wave: 16 rows x 64 kv cols)
            f32x4 accs[4] = {};
#pragma unroll
            for (int ks = 0; ks < 4; ++ks)
#pragma unroll
                for (int j = 0; j < 4; ++j) {
                    bf16x8 bk = *(const bf16x8*)(Ks + (j * 16 + l16) * 128 + ks * 32 + quad * 8);
                    accs[j] = MFMA16(aq[ks], bk, accs[j]);
                }

            // online softmax, per C-layout row (quad*4 + r)
#pragma unroll
            for (int r = 0; r < 4; ++r) {
                const int qrow = q0 + wave * 16 + quad * 4 + r;
                float s[4];
                float mx = -30000.f;
#pragma unroll
                for (int j = 0; j < 4; ++j) {
                    s[j] = accs[j][r] * scale;
                    if (kv0 + j * 16 + l16 > qrow) s[j] = -30000.f;   // causal
                    mx = fmaxf(mx, s[j]);
                }
                mx = fmaxf(mx, __shfl_xor(mx, 1, 64));
                mx = fmaxf(mx, __shfl_xor(mx, 2, 64));
                mx = fmaxf(mx, __shfl_xor(mx, 4, 64));
                mx = fmaxf(mx, __shfl_xor(mx, 8, 64));
                float mnew  = fmaxf(m_r[r], mx);
                float alpha = __expf(fmaxf(m_r[r] - mnew, -80.f));
                float rs = 0.f;
#pragma unroll
                for (int j = 0; j < 4; ++j) {
                    float p = __expf(fmaxf(s[j] - mnew, -80.f));
                    rs += p;
                    Pl[wave][(quad * 4 + r) * 72 + j * 16 + l16] = (bf16_t)p;
                }
                rs += __shfl_xor(rs, 1, 64);
                rs += __shfl_xor(rs, 2, 64);
                rs += __shfl_xor(rs, 4, 64);
                rs += __shfl_xor(rs, 8, 64);
                l_r[r] = l_r[r] * alpha + rs;
                m_r[r] = mnew;
#pragma unroll
                for (int nt = 0; nt < 8; ++nt) acc_o[nt][r] *= alpha;
            }

            __syncthreads();   // P writes visible before PV reads

            // O += P V  (P A-layout from padded Pl; V from swizzled Vt)
#pragma unroll
            for (int ks2 = 0; ks2 < 2; ++ks2) {
                bf16x8 ap = *(const bf16x8*)(&Pl[wave][l16 * 72 + ks2 * 32 + quad * 8]);
                const int kb_r = ks2 * 4 + quad;
#pragma unroll
                for (int nt = 0; nt < 8; ++nt) {
                    const int d = nt * 16 + l16;
                    bf16x8 bv = *(const bf16x8*)(Vt + d * 64 + ((kb_r ^ (d & 7)) << 3));
                    acc_o[nt] = MFMA16(ap, bv, acc_o[nt]);
                }
            }
        }

        // write O (divide by l), layout [b*S + q][h*128 + d]
#pragma unroll
        for (int r = 0; r < 4; ++r) {
            float inv = 1.f / fmaxf(l_r[r], 1e-30f);
            size_t orow = (size_t)b * 2048 + q0 + wave * 16 + quad * 4 + r;
#pragma unroll
            for (int nt = 0; nt < 8; ++nt)
                O[orow * 2048 + h * 128 + nt * 16 + l16] = (bf16_t)(acc_o[nt][r] * inv);
        }
    }
}

// ---------------------------------------------------------------------------
// Launch. All inputs fp32 (reference dtypes); output fp32; bf16 MFMA internal.
// Workspace peak ~39.1M bf16 elements = 78.2 MB.
// ---------------------------------------------------------------------------
extern "C" void kernel_launch(void* const* d_in, const int* in_sizes, int n_in,
                              void* d_out, int out_size, void* d_ws, size_t ws_size,
                              hipStream_t stream)
{
    const float* x   = (const float*)d_in[0];
    // d_in[1] = attention_mask (causal) — applied analytically
    const float* qw  = (const float*)d_in[2];
    const float* kw  = (const float*)d_in[3];
    const float* vw  = (const float*)d_in[4];
    const float* ow  = (const float*)d_in[5];
    const float* gw  = (const float*)d_in[6];
    const float* uw  = (const float*)d_in[7];
    const float* dw  = (const float*)d_in[8];
    const float* ln1 = (const float*)d_in[9];
    const float* ln2 = (const float*)d_in[10];
    float*  out = (float*)d_out;
    bf16_t* ws  = (bf16_t*)d_ws;

    const size_t ME = 1ull << 20;        // 1M elements
    bf16_t* h1 = ws;                     // [0, 8M)   ln1(x), later ln2(h)
    bf16_t* qb = ws + 8  * ME;           // [8,16M)   q, later hb
    bf16_t* kb = ws + 16 * ME;           // [16,20M)  k
    bf16_t* vb = ws + 20 * ME;           // [20,24M)  v
    bf16_t* ab = (bf16_t*)d_out;         // attn out: d_out as bf16 scratch
    bf16_t* hb = ws + 8  * ME;           // [8,16M)   h = x + attn (q dead)
    bf16_t* gb = ws + 16 * ME;           // [16,39.1M) swiglu out (k/v dead)

    dim3 blk(256);
    rmsnorm_f32<<<4096, blk, 0, stream>>>(x, ln1, h1);
    gemm_bt<<<dim3(16, 32), blk, 0, stream>>>(h1, qw, nullptr, nullptr, qb, nullptr, 4096, 2048, 2048, 0);
    gemm_bt<<<dim3( 8, 32), blk, 0, stream>>>(h1, kw, nullptr, nullptr, kb, nullptr, 4096, 1024, 2048, 0);
    gemm_bt<<<dim3( 8, 32), blk, 0, stream>>>(h1, vw, nullptr, nullptr, vb, nullptr, 4096, 1024, 2048, 0);
    attn_fwd<<<dim3(16, 32), blk, 0, stream>>>(qb, kb, vb, ab);
    gemm_bt<<<dim3(16, 32), blk, 0, stream>>>(ab, ow, x, nullptr, hb, nullptr, 4096, 2048, 2048, 1);
    rmsnorm_bf16<<<4096, blk, 0, stream>>>(hb, ln2, h1);
    gemm_gateup<<<dim3(44, 32), blk, 0, stream>>>(h1, gw, uw, gb, 4096, 5632, 2048);
    gemm_bt<<<dim3(16, 32), blk, 0, stream>>>(gb, dw, nullptr, hb, nullptr, out, 4096, 2048, 5632, 2);
}

// Round 5
// 998.469 us; speedup vs baseline: 1.5402x; 1.2094x over previous
//
#include <hip/hip_runtime.h>
#include <stdint.h>

typedef __bf16 bf16_t;
typedef __bf16 bf16x8 __attribute__((ext_vector_type(8)));
typedef __bf16 bf16x4 __attribute__((ext_vector_type(4)));
typedef float  f32x4  __attribute__((ext_vector_type(4)));

#define MFMA16(a, b, c) __builtin_amdgcn_mfma_f32_16x16x32_bf16((a), (b), (c), 0, 0, 0)

// Async global->LDS 16B/lane. LDS dest is wave-uniform base + lane*16; our
// lds ptr is computed as base + lane*16, matching the HW contract (m97/m104).
__device__ __forceinline__ void load_lds16(const bf16_t* g, bf16_t* l)
{
    __builtin_amdgcn_global_load_lds(
        (const __attribute__((address_space(1))) uint32_t*)(uintptr_t)g,
        (__attribute__((address_space(3))) uint32_t*)(uint32_t)(uintptr_t)l,
        16, 0, 0);
}

// ---------------------------------------------------------------------------
// Weight convert fp32 -> bf16, 8 elems/thread
// ---------------------------------------------------------------------------
__global__ __launch_bounds__(256)
void wconv(const float* __restrict__ X, bf16_t* __restrict__ Y, int n)
{
    int i = (blockIdx.x * 256 + threadIdx.x) * 8;
    if (i >= n) return;
    f32x4 a = *(const f32x4*)(X + i);
    f32x4 b = *(const f32x4*)(X + i + 4);
    bf16x8 y;
#pragma unroll
    for (int e = 0; e < 4; ++e) { y[e] = (bf16_t)a[e]; y[e + 4] = (bf16_t)b[e]; }
    *(bf16x8*)(Y + i) = y;
}

// ---------------------------------------------------------------------------
// RMSNorm (fp32 in -> bf16 out)
// ---------------------------------------------------------------------------
__global__ __launch_bounds__(256)
void rmsnorm_f32(const float* __restrict__ X, const float* __restrict__ Wt,
                 bf16_t* __restrict__ Y)
{
    __shared__ float red[4];
    const int tid = threadIdx.x;
    const size_t row = blockIdx.x;
    const float* x = X + row * 2048;

    f32x4 x0 = *(const f32x4*)(x + tid * 8);
    f32x4 x1 = *(const f32x4*)(x + tid * 8 + 4);
    float ss = 0.f;
#pragma unroll
    for (int e = 0; e < 4; ++e) ss += x0[e] * x0[e] + x1[e] * x1[e];
#pragma unroll
    for (int off = 32; off; off >>= 1) ss += __shfl_xor(ss, off, 64);
    if ((tid & 63) == 0) red[tid >> 6] = ss;
    __syncthreads();
    float tot = red[0] + red[1] + red[2] + red[3];
    float scale = rsqrtf(tot * (1.f / 2048.f) + 1e-6f);

    f32x4 w0 = *(const f32x4*)(Wt + tid * 8);
    f32x4 w1 = *(const f32x4*)(Wt + tid * 8 + 4);
    bf16x8 yv;
#pragma unroll
    for (int e = 0; e < 4; ++e) {
        yv[e]     = (bf16_t)(x0[e] * scale * w0[e]);
        yv[e + 4] = (bf16_t)(x1[e] * scale * w1[e]);
    }
    *(bf16x8*)(Y + row * 2048 + tid * 8) = yv;
}

// ---------------------------------------------------------------------------
// RMSNorm (bf16 in -> bf16 out), fp32 gamma
// ---------------------------------------------------------------------------
__global__ __launch_bounds__(256)
void rmsnorm_bf16(const bf16_t* __restrict__ X, const float* __restrict__ Wt,
                  bf16_t* __restrict__ Y)
{
    __shared__ float red[4];
    const int tid = threadIdx.x;
    const size_t row = blockIdx.x;

    bf16x8 xv = *(const bf16x8*)(X + row * 2048 + tid * 8);
    float xf[8];
    float ss = 0.f;
#pragma unroll
    for (int e = 0; e < 8; ++e) { xf[e] = (float)xv[e]; ss += xf[e] * xf[e]; }
#pragma unroll
    for (int off = 32; off; off >>= 1) ss += __shfl_xor(ss, off, 64);
    if ((tid & 63) == 0) red[tid >> 6] = ss;
    __syncthreads();
    float tot = red[0] + red[1] + red[2] + red[3];
    float scale = rsqrtf(tot * (1.f / 2048.f) + 1e-6f);

    f32x4 w0 = *(const f32x4*)(Wt + tid * 8);
    f32x4 w1 = *(const f32x4*)(Wt + tid * 8 + 4);
    bf16x8 yv;
#pragma unroll
    for (int e = 0; e < 4; ++e) {
        yv[e]     = (bf16_t)(xf[e] * scale * w0[e]);
        yv[e + 4] = (bf16_t)(xf[e + 4] * scale * w1[e]);
    }
    *(bf16x8*)(Y + row * 2048 + tid * 8) = yv;
}

// ---------------------------------------------------------------------------
// FAST PATH GEMM (pure bf16, global_load_lds staging, m97 structure):
// C[M,N] = A[M,K] @ W[N,K]^T, fp32 acc.
// mode 0: Cb = acc | mode 1: Cb = acc + Rf(fp32) | mode 2: Cf = acc + Rb(bf16)
// ---------------------------------------------------------------------------
__global__ __launch_bounds__(256, 2)
void gemm_bb(const bf16_t* __restrict__ A, const bf16_t* __restrict__ W,
             const float* __restrict__ Rf, const bf16_t* __restrict__ Rb,
             bf16_t* __restrict__ Cb, float* __restrict__ Cf,
             int M, int N, int K, int mode)
{
    __shared__ bf16_t As[128 * 64];
    __shared__ bf16_t Ws[128 * 64];

    const int tid  = threadIdx.x;
    const int lane = tid & 63, wave = tid >> 6;
    const int quad = lane >> 4, l16 = lane & 15;
    const int m0 = blockIdx.y * 128, n0 = blockIdx.x * 128;
    const int wm = (wave >> 1) * 64, wn = (wave & 1) * 64;

    // staging address decomposition: u = i*256 + tid -> row = i*32 + tid/8,
    // col = (tid&7)*8; LDS offset = u*16B (lane-contiguous, per HW contract)
    const bf16_t* Ab = A + (size_t)(m0 + (tid >> 3)) * K + ((tid & 7) << 3);
    const bf16_t* Wb = W + (size_t)(n0 + (tid >> 3)) * K + ((tid & 7) << 3);

    f32x4 acc[4][4] = {};

    for (int k0 = 0; k0 < K; k0 += 64) {
        __syncthreads();                 // prior MFMA reads of LDS complete
#pragma unroll
        for (int i = 0; i < 4; ++i) {
            load_lds16(Ab + (size_t)(i * 32) * K + k0, As + (i * 256 + tid) * 8);
            load_lds16(Wb + (size_t)(i * 32) * K + k0, Ws + (i * 256 + tid) * 8);
        }
        __syncthreads();                 // drains vmcnt (compiler-inserted)

#pragma unroll
        for (int ks = 0; ks < 64; ks += 32) {
            bf16x8 af[4], bfr[4];
#pragma unroll
            for (int i = 0; i < 4; ++i)
                af[i] = *(const bf16x8*)(As + (wm + i * 16 + l16) * 64 + ks + quad * 8);
#pragma unroll
            for (int j = 0; j < 4; ++j)
                bfr[j] = *(const bf16x8*)(Ws + (wn + j * 16 + l16) * 64 + ks + quad * 8);
#pragma unroll
            for (int i = 0; i < 4; ++i)
#pragma unroll
                for (int j = 0; j < 4; ++j)
                    acc[i][j] = MFMA16(af[i], bfr[j], acc[i][j]);
        }
    }

#pragma unroll
    for (int i = 0; i < 4; ++i)
#pragma unroll
        for (int j = 0; j < 4; ++j)
#pragma unroll
            for (int r = 0; r < 4; ++r) {
                size_t row = (size_t)(m0 + wm + i * 16 + quad * 4 + r);
                size_t col = (size_t)(n0 + wn + j * 16 + l16);
                float v = acc[i][j][r];
                if (mode == 1) v += Rf[row * (size_t)N + col];
                if (mode == 2)
                    Cf[row * (size_t)N + col] = v + (float)Rb[row * (size_t)N + col];
                else
                    Cb[row * (size_t)N + col] = (bf16_t)v;
            }
}

// ---------------------------------------------------------------------------
// FAST PATH fused gate+up + SwiGLU (pure bf16, global_load_lds staging)
// ---------------------------------------------------------------------------
__global__ __launch_bounds__(256, 2)
void gateup_bb(const bf16_t* __restrict__ A, const bf16_t* __restrict__ G,
               const bf16_t* __restrict__ U, bf16_t* __restrict__ C,
               int M, int N, int K)
{
    __shared__ bf16_t As[128 * 64];
    __shared__ bf16_t Gs[128 * 64];
    __shared__ bf16_t Us[128 * 64];

    const int tid  = threadIdx.x;
    const int lane = tid & 63, wave = tid >> 6;
    const int quad = lane >> 4, l16 = lane & 15;
    const int m0 = blockIdx.y * 128, n0 = blockIdx.x * 128;
    const int wm = (wave >> 1) * 64, wn = (wave & 1) * 64;

    const bf16_t* Ab = A + (size_t)(m0 + (tid >> 3)) * K + ((tid & 7) << 3);
    const bf16_t* Gb = G + (size_t)(n0 + (tid >> 3)) * K + ((tid & 7) << 3);
    const bf16_t* Ub = U + (size_t)(n0 + (tid >> 3)) * K + ((tid & 7) << 3);

    f32x4 accg[4][4] = {};
    f32x4 accu[4][4] = {};

    for (int k0 = 0; k0 < K; k0 += 64) {
        __syncthreads();
#pragma unroll
        for (int i = 0; i < 4; ++i) {
            load_lds16(Ab + (size_t)(i * 32) * K + k0, As + (i * 256 + tid) * 8);
            load_lds16(Gb + (size_t)(i * 32) * K + k0, Gs + (i * 256 + tid) * 8);
            load_lds16(Ub + (size_t)(i * 32) * K + k0, Us + (i * 256 + tid) * 8);
        }
        __syncthreads();

#pragma unroll
        for (int ks = 0; ks < 64; ks += 32) {
            bf16x8 af[4], bg[4], bu[4];
#pragma unroll
            for (int i = 0; i < 4; ++i)
                af[i] = *(const bf16x8*)(As + (wm + i * 16 + l16) * 64 + ks + quad * 8);
#pragma unroll
            for (int j = 0; j < 4; ++j) {
                bg[j] = *(const bf16x8*)(Gs + (wn + j * 16 + l16) * 64 + ks + quad * 8);
                bu[j] = *(const bf16x8*)(Us + (wn + j * 16 + l16) * 64 + ks + quad * 8);
            }
#pragma unroll
            for (int i = 0; i < 4; ++i)
#pragma unroll
                for (int j = 0; j < 4; ++j) {
                    accg[i][j] = MFMA16(af[i], bg[j], accg[i][j]);
                    accu[i][j] = MFMA16(af[i], bu[j], accu[i][j]);
                }
        }
    }

#pragma unroll
    for (int i = 0; i < 4; ++i)
#pragma unroll
        for (int j = 0; j < 4; ++j)
#pragma unroll
            for (int r = 0; r < 4; ++r) {
                size_t row = (size_t)(m0 + wm + i * 16 + quad * 4 + r);
                size_t col = (size_t)(n0 + wn + j * 16 + l16);
                float g = accg[i][j][r];
                float u = accu[i][j][r];
                float sig = 1.f / (1.f + __expf(fminf(-g, 80.f)));
                C[row * (size_t)N + col] = (bf16_t)(g * sig * u);
            }
}

// ---------------------------------------------------------------------------
// FALLBACK GEMM (round-4 path, fp32 weights staged in registers)
// ---------------------------------------------------------------------------
__global__ __launch_bounds__(256, 2)
void gemm_bt(const bf16_t* __restrict__ A, const float* __restrict__ W,
             const float* __restrict__ Rf, const bf16_t* __restrict__ Rb,
             bf16_t* __restrict__ Cb, float* __restrict__ Cf,
             int M, int N, int K, int mode)
{
    __shared__ bf16_t As[128 * 64];
    __shared__ bf16_t Ws[128 * 64];

    const int tid  = threadIdx.x;
    const int lane = tid & 63, wave = tid >> 6;
    const int quad = lane >> 4, l16 = lane & 15;
    const int m0 = blockIdx.y * 128, n0 = blockIdx.x * 128;
    const int wm = (wave >> 1) * 64, wn = (wave & 1) * 64;

    f32x4 acc[4][4] = {};

    for (int k0 = 0; k0 < K; k0 += 64) {
        bf16x8 ra[4];
        bf16x4 rw[8];
#pragma unroll
        for (int i = 0; i < 4; ++i) {
            int u = i * 256 + tid;
            int r = u >> 3, c = (u & 7) << 3;
            ra[i] = *(const bf16x8*)(A + (size_t)(m0 + r) * K + k0 + c);
        }
#pragma unroll
        for (int i = 0; i < 8; ++i) {
            int u = i * 256 + tid;
            int r = u >> 4, c = (u & 15) << 2;
            f32x4 w4 = *(const f32x4*)(W + (size_t)(n0 + r) * K + k0 + c);
#pragma unroll
            for (int e = 0; e < 4; ++e) rw[i][e] = (bf16_t)w4[e];
        }
        __syncthreads();
#pragma unroll
        for (int i = 0; i < 4; ++i)
            *(bf16x8*)(As + (i * 256 + tid) * 8) = ra[i];
#pragma unroll
        for (int i = 0; i < 8; ++i)
            *(bf16x4*)(Ws + (i * 256 + tid) * 4) = rw[i];
        __syncthreads();

#pragma unroll
        for (int ks = 0; ks < 64; ks += 32) {
            bf16x8 af[4], bfr[4];
#pragma unroll
            for (int i = 0; i < 4; ++i)
                af[i] = *(const bf16x8*)(As + (wm + i * 16 + l16) * 64 + ks + quad * 8);
#pragma unroll
            for (int j = 0; j < 4; ++j)
                bfr[j] = *(const bf16x8*)(Ws + (wn + j * 16 + l16) * 64 + ks + quad * 8);
#pragma unroll
            for (int i = 0; i < 4; ++i)
#pragma unroll
                for (int j = 0; j < 4; ++j)
                    acc[i][j] = MFMA16(af[i], bfr[j], acc[i][j]);
        }
    }

#pragma unroll
    for (int i = 0; i < 4; ++i)
#pragma unroll
        for (int j = 0; j < 4; ++j)
#pragma unroll
            for (int r = 0; r < 4; ++r) {
                size_t row = (size_t)(m0 + wm + i * 16 + quad * 4 + r);
                size_t col = (size_t)(n0 + wn + j * 16 + l16);
                float v = acc[i][j][r];
                if (mode == 1) v += Rf[row * (size_t)N + col];
                if (mode == 2)
                    Cf[row * (size_t)N + col] = v + (float)Rb[row * (size_t)N + col];
                else
                    Cb[row * (size_t)N + col] = (bf16_t)v;
            }
}

// ---------------------------------------------------------------------------
// FALLBACK fused gate+up (round-4 path, fp32 weights)
// ---------------------------------------------------------------------------
__global__ __launch_bounds__(256, 2)
void gemm_gateup(const bf16_t* __restrict__ A, const float* __restrict__ G,
                 const float* __restrict__ U, bf16_t* __restrict__ C,
                 int M, int N, int K)
{
    __shared__ bf16_t As[128 * 64];
    __shared__ bf16_t Gs[128 * 64];
    __shared__ bf16_t Us[128 * 64];

    const int tid  = threadIdx.x;
    const int lane = tid & 63, wave = tid >> 6;
    const int quad = lane >> 4, l16 = lane & 15;
    const int m0 = blockIdx.y * 128, n0 = blockIdx.x * 128;
    const int wm = (wave >> 1) * 64, wn = (wave & 1) * 64;

    f32x4 accg[4][4] = {};
    f32x4 accu[4][4] = {};

    for (int k0 = 0; k0 < K; k0 += 64) {
        bf16x8 ra[4];
        bf16x4 rg[8], ru[8];
#pragma unroll
        for (int i = 0; i < 4; ++i) {
            int u = i * 256 + tid;
            int r = u >> 3, c = (u & 7) << 3;
            ra[i] = *(const bf16x8*)(A + (size_t)(m0 + r) * K + k0 + c);
        }
#pragma unroll
        for (int i = 0; i < 8; ++i) {
            int u = i * 256 + tid;
            int r = u >> 4, c = (u & 15) << 2;
            f32x4 g4 = *(const f32x4*)(G + (size_t)(n0 + r) * K + k0 + c);
            f32x4 u4 = *(const f32x4*)(U + (size_t)(n0 + r) * K + k0 + c);
#pragma unroll
            for (int e = 0; e < 4; ++e) { rg[i][e] = (bf16_t)g4[e]; ru[i][e] = (bf16_t)u4[e]; }
        }
        __syncthreads();
#pragma unroll
        for (int i = 0; i < 4; ++i)
            *(bf16x8*)(As + (i * 256 + tid) * 8) = ra[i];
#pragma unroll
        for (int i = 0; i < 8; ++i) {
            *(bf16x4*)(Gs + (i * 256 + tid) * 4) = rg[i];
            *(bf16x4*)(Us + (i * 256 + tid) * 4) = ru[i];
        }
        __syncthreads();

#pragma unroll
        for (int ks = 0; ks < 64; ks += 32) {
            bf16x8 af[4], bg[4], bu[4];
#pragma unroll
            for (int i = 0; i < 4; ++i)
                af[i] = *(const bf16x8*)(As + (wm + i * 16 + l16) * 64 + ks + quad * 8);
#pragma unroll
            for (int j = 0; j < 4; ++j) {
                bg[j] = *(const bf16x8*)(Gs + (wn + j * 16 + l16) * 64 + ks + quad * 8);
                bu[j] = *(const bf16x8*)(Us + (wn + j * 16 + l16) * 64 + ks + quad * 8);
            }
#pragma unroll
            for (int i = 0; i < 4; ++i)
#pragma unroll
                for (int j = 0; j < 4; ++j) {
                    accg[i][j] = MFMA16(af[i], bg[j], accg[i][j]);
                    accu[i][j] = MFMA16(af[i], bu[j], accu[i][j]);
                }
        }
    }

#pragma unroll
    for (int i = 0; i < 4; ++i)
#pragma unroll
        for (int j = 0; j < 4; ++j)
#pragma unroll
            for (int r = 0; r < 4; ++r) {
                size_t row = (size_t)(m0 + wm + i * 16 + quad * 4 + r);
                size_t col = (size_t)(n0 + wn + j * 16 + l16);
                float g = accg[i][j][r];
                float u = accu[i][j][r];
                float sig = 1.f / (1.f + __expf(fminf(-g, 80.f)));
                C[row * (size_t)N + col] = (bf16_t)(g * sig * u);
            }
}

// ---------------------------------------------------------------------------
// Flash attention fwd (round-4 version: swizzled Vt, padded Pl, paired q-tiles)
// ---------------------------------------------------------------------------
__global__ __launch_bounds__(256, 2)
void attn_fwd(const bf16_t* __restrict__ Q, const bf16_t* __restrict__ Kg,
              const bf16_t* __restrict__ Vg, bf16_t* __restrict__ O)
{
    __shared__ bf16_t Ks[64 * 128];
    __shared__ bf16_t Vt[128 * 64];      // Vt[d][k], k-blocks XOR-swizzled by d&7
    __shared__ bf16_t Pl[4][16 * 72];    // padded stride 72

    const int tid  = threadIdx.x;
    const int lane = tid & 63, wave = tid >> 6;
    const int quad = lane >> 4, l16 = lane & 15;
    const int bh = blockIdx.y, b = bh >> 4, h = bh & 15;

    const bf16_t* Qh = Q  + (size_t)b * 2048 * 2048 + (size_t)h * 128;
    const bf16_t* Kh = Kg + (size_t)b * 2048 * 1024 + (size_t)(h >> 1) * 128;
    const bf16_t* Vh = Vg + (size_t)b * 2048 * 1024 + (size_t)(h >> 1) * 128;

    const float scale = 0.08838834764831845f;   // 1/sqrt(128)

#pragma unroll 1
    for (int pass = 0; pass < 2; ++pass) {
        const int qt = pass ? (31 - (int)blockIdx.x) : (int)blockIdx.x;
        const int q0 = qt * 64;

        bf16x8 aq[4];
#pragma unroll
        for (int ks = 0; ks < 4; ++ks)
            aq[ks] = *(const bf16x8*)(Qh + (size_t)(q0 + wave * 16 + l16) * 2048 + ks * 32 + quad * 8);

        float m_r[4] = { -30000.f, -30000.f, -30000.f, -30000.f };
        float l_r[4] = { 0.f, 0.f, 0.f, 0.f };
        f32x4 acc_o[8] = {};

        const int ntiles = qt + 1;

        for (int t = 0; t < ntiles; ++t) {
            const int kv0 = t * 64;
            __syncthreads();
#pragma unroll
            for (int i = 0; i < 4; ++i) {
                int u = i * 256 + tid;
                int rk = u >> 4, c = (u & 15) << 3;
                *(bf16x8*)(Ks + u * 8) =
                    *(const bf16x8*)(Kh + (size_t)(kv0 + rk) * 1024 + c);
            }
#pragma unroll
            for (int it = 0; it < 4; ++it) {
                int v = it * 256 + tid;
                int d = v & 127, kb = v >> 7;
                bf16x8 vt8;
#pragma unroll
                for (int j = 0; j < 8; ++j)
                    vt8[j] = Vh[(size_t)(kv0 + kb * 8 + j) * 1024 + d];
                *(bf16x8*)(Vt + d * 64 + ((kb ^ (d & 7)) << 3)) = vt8;
            }
            __syncthreads();

            f32x4 accs[4] = {};
#pragma unroll
            for (int ks = 0; ks < 4; ++ks)
#pragma unroll
                for (int j = 0; j < 4; ++j) {
                    bf16x8 bk = *(const bf16x8*)(Ks + (j * 16 + l16) * 128 + ks * 32 + quad * 8);
                    accs[j] = MFMA16(aq[ks], bk, accs[j]);
                }

#pragma unroll
            for (int r = 0; r < 4; ++r) {
                const int qrow = q0 + wave * 16 + quad * 4 + r;
                float s[4];
                float mx = -30000.f;
#pragma unroll
                for (int j = 0; j < 4; ++j) {
                    s[j] = accs[j][r] * scale;
                    if (kv0 + j * 16 + l16 > qrow) s[j] = -30000.f;
                    mx = fmaxf(mx, s[j]);
                }
                mx = fmaxf(mx, __shfl_xor(mx, 1, 64));
                mx = fmaxf(mx, __shfl_xor(mx, 2, 64));
                mx = fmaxf(mx, __shfl_xor(mx, 4, 64));
                mx = fmaxf(mx, __shfl_xor(mx, 8, 64));
                float mnew  = fmaxf(m_r[r], mx);
                float alpha = __expf(fmaxf(m_r[r] - mnew, -80.f));
                float rs = 0.f;
#pragma unroll
                for (int j = 0; j < 4; ++j) {
                    float p = __expf(fmaxf(s[j] - mnew, -80.f));
                    rs += p;
                    Pl[wave][(quad * 4 + r) * 72 + j * 16 + l16] = (bf16_t)p;
                }
                rs += __shfl_xor(rs, 1, 64);
                rs += __shfl_xor(rs, 2, 64);
                rs += __shfl_xor(rs, 4, 64);
                rs += __shfl_xor(rs, 8, 64);
                l_r[r] = l_r[r] * alpha + rs;
                m_r[r] = mnew;
#pragma unroll
                for (int nt = 0; nt < 8; ++nt) acc_o[nt][r] *= alpha;
            }

            __syncthreads();

#pragma unroll
            for (int ks2 = 0; ks2 < 2; ++ks2) {
                bf16x8 ap = *(const bf16x8*)(&Pl[wave][l16 * 72 + ks2 * 32 + quad * 8]);
                const int kb_r = ks2 * 4 + quad;
#pragma unroll
                for (int nt = 0; nt < 8; ++nt) {
                    const int d = nt * 16 + l16;
                    bf16x8 bv = *(const bf16x8*)(Vt + d * 64 + ((kb_r ^ (d & 7)) << 3));
                    acc_o[nt] = MFMA16(ap, bv, acc_o[nt]);
                }
            }
        }

#pragma unroll
        for (int r = 0; r < 4; ++r) {
            float inv = 1.f / fmaxf(l_r[r], 1e-30f);
            size_t orow = (size_t)b * 2048 + q0 + wave * 16 + quad * 4 + r;
#pragma unroll
            for (int nt = 0; nt < 8; ++nt)
                O[orow * 2048 + h * 128 + nt * 16 + l16] = (bf16_t)(acc_o[nt][r] * inv);
        }
    }
}

// ---------------------------------------------------------------------------
// Launch. Fast path (ws >= 174 MB): pre-convert weights to bf16 once, then
// pure-bf16 GEMMs with global_load_lds. Fallback: round-4 mixed path.
// Branch is on ws_size (constant across calls) -> graph-capture safe.
// ---------------------------------------------------------------------------
extern "C" void kernel_launch(void* const* d_in, const int* in_sizes, int n_in,
                              void* d_out, int out_size, void* d_ws, size_t ws_size,
                              hipStream_t stream)
{
    const float* x   = (const float*)d_in[0];
    const float* qw  = (const float*)d_in[2];
    const float* kw  = (const float*)d_in[3];
    const float* vw  = (const float*)d_in[4];
    const float* ow  = (const float*)d_in[5];
    const float* gw  = (const float*)d_in[6];
    const float* uw  = (const float*)d_in[7];
    const float* dw  = (const float*)d_in[8];
    const float* ln1 = (const float*)d_in[9];
    const float* ln2 = (const float*)d_in[10];
    float*  out = (float*)d_out;
    bf16_t* ws  = (bf16_t*)d_ws;

    dim3 blk(256);
    const size_t NEED = 87031808ull * 2;   // 174 MB

    if (ws_size >= NEED) {
        // ---- fast path: bf16 weights + global_load_lds GEMMs ----
        bf16_t* wq = ws;                      // 4,194,304
        bf16_t* wk = ws + 4194304;            // 2,097,152
        bf16_t* wv = ws + 6291456;            // 2,097,152
        bf16_t* wo = ws + 8388608;            // 4,194,304
        bf16_t* wg = ws + 12582912;           // 11,534,336
        bf16_t* wu = ws + 24117248;           // 11,534,336
        bf16_t* wd = ws + 35651584;           // 11,534,336
        bf16_t* h1 = ws + 47185920;           // 8,388,608
        bf16_t* qb = ws + 55574528;           // 8,388,608 (later hb)
        bf16_t* kb = ws + 63963136;           // 4,194,304 (later gb)
        bf16_t* vb = ws + 68157440;           // 4,194,304
        bf16_t* ab = (bf16_t*)d_out;          // attn out scratch in d_out
        bf16_t* hb = qb;
        bf16_t* gb = kb;                      // 23,068,672 ends at 87,031,808

        wconv<<<2048, blk, 0, stream>>>(qw, wq, 4194304);
        wconv<<<1024, blk, 0, stream>>>(kw, wk, 2097152);
        wconv<<<1024, blk, 0, stream>>>(vw, wv, 2097152);
        wconv<<<2048, blk, 0, stream>>>(ow, wo, 4194304);
        wconv<<<5632, blk, 0, stream>>>(gw, wg, 11534336);
        wconv<<<5632, blk, 0, stream>>>(uw, wu, 11534336);
        wconv<<<5632, blk, 0, stream>>>(dw, wd, 11534336);

        rmsnorm_f32<<<4096, blk, 0, stream>>>(x, ln1, h1);
        gemm_bb<<<dim3(16, 32), blk, 0, stream>>>(h1, wq, nullptr, nullptr, qb, nullptr, 4096, 2048, 2048, 0);
        gemm_bb<<<dim3( 8, 32), blk, 0, stream>>>(h1, wk, nullptr, nullptr, kb, nullptr, 4096, 1024, 2048, 0);
        gemm_bb<<<dim3( 8, 32), blk, 0, stream>>>(h1, wv, nullptr, nullptr, vb, nullptr, 4096, 1024, 2048, 0);
        attn_fwd<<<dim3(16, 32), blk, 0, stream>>>(qb, kb, vb, ab);
        gemm_bb<<<dim3(16, 32), blk, 0, stream>>>(ab, wo, x, nullptr, hb, nullptr, 4096, 2048, 2048, 1);
        rmsnorm_bf16<<<4096, blk, 0, stream>>>(hb, ln2, h1);
        gateup_bb<<<dim3(44, 32), blk, 0, stream>>>(h1, wg, wu, gb, 4096, 5632, 2048);
        gemm_bb<<<dim3(16, 32), blk, 0, stream>>>(gb, wd, nullptr, hb, nullptr, out, 4096, 2048, 5632, 2);
    } else {
        // ---- fallback: round-4 mixed path (78 MB) ----
        const size_t ME = 1ull << 20;
        bf16_t* h1 = ws;
        bf16_t* qb = ws + 8  * ME;
        bf16_t* kb = ws + 16 * ME;
        bf16_t* vb = ws + 20 * ME;
        bf16_t* ab = (bf16_t*)d_out;
        bf16_t* hb = ws + 8  * ME;
        bf16_t* gb = ws + 16 * ME;

        rmsnorm_f32<<<4096, blk, 0, stream>>>(x, ln1, h1);
        gemm_bt<<<dim3(16, 32), blk, 0, stream>>>(h1, qw, nullptr, nullptr, qb, nullptr, 4096, 2048, 2048, 0);
        gemm_bt<<<dim3( 8, 32), blk, 0, stream>>>(h1, kw, nullptr, nullptr, kb, nullptr, 4096, 1024, 2048, 0);
        gemm_bt<<<dim3( 8, 32), blk, 0, stream>>>(h1, vw, nullptr, nullptr, vb, nullptr, 4096, 1024, 2048, 0);
        attn_fwd<<<dim3(16, 32), blk, 0, stream>>>(qb, kb, vb, ab);
        gemm_bt<<<dim3(16, 32), blk, 0, stream>>>(ab, ow, x, nullptr, hb, nullptr, 4096, 2048, 2048, 1);
        rmsnorm_bf16<<<4096, blk, 0, stream>>>(hb, ln2, h1);
        gemm_gateup<<<dim3(44, 32), blk, 0, stream>>>(h1, gw, uw, gb, 4096, 5632, 2048);
        gemm_bt<<<dim3(16, 32), blk, 0, stream>>>(gb, dw, nullptr, hb, nullptr, out, 4096, 2048, 5632, 2);
    }
}